// Round 1
// baseline (460.397 us; speedup 1.0000x reference)
//
#include <hip/hip_runtime.h>
#include <stdint.h>

#define BATCH 8192   // GEMM M and N
#define DIM   2048   // GEMM K

typedef unsigned short u16;
typedef unsigned int   u32;

using v8bf = __bf16 __attribute__((ext_vector_type(8)));
using v4f  = float  __attribute__((ext_vector_type(4)));

// f32 -> bf16 round-to-nearest-even (no NaN handling needed: Gaussian inputs)
__device__ __forceinline__ u16 f2bf(float f) {
  u32 u = __float_as_uint(f);
  u32 r = (u + 0x7FFFu + ((u >> 16) & 1u)) >> 16;
  return (u16)r;
}
__device__ __forceinline__ u32 pack2(float lo, float hi) {
  return (u32)f2bf(lo) | ((u32)f2bf(hi) << 16);
}

// async global->LDS, 16B per lane (the m93->m97 1.69x lever)
__device__ __forceinline__ void gl_lds16(const void* g, void* l) {
  __builtin_amdgcn_global_load_lds(
      (const __attribute__((address_space(1))) u32*)g,
      (__attribute__((address_space(3))) u32*)l, 16, 0, 0);
}

// C = L * T^T (M=N=8192, K=2048), never materialized: each block accumulates
// sum of squares of its 128x128 tile and atomically adds to d_acc.
// PRE=true : operands are pre-converted bf16 (in ws), staged via global_load_lds.
// PRE=false: operands are f32 in HBM, converted during staging (ws-less fallback).
template<bool PRE>
__global__ __launch_bounds__(256) void gemm_sq_kernel(
    const void* __restrict__ Ap, const void* __restrict__ Bp,
    float* __restrict__ d_acc)
{
  __shared__ u16 lsA[128 * 32];   // [m][k] bf16, k-contiguous (8 KB)
  __shared__ u16 lsB[128 * 32];   // [n][k] bf16
  __shared__ float red[4];

  const int tid  = threadIdx.x;
  const int m0   = blockIdx.y * 128;
  const int n0   = blockIdx.x * 128;
  const int wave = tid >> 6;
  const int lane = tid & 63;
  const int wr   = (wave >> 1) * 64;   // wave's 64x64 quadrant
  const int wc   = (wave & 1) * 64;
  const int lm   = lane & 15;          // MFMA A/B operand: m(or n) = lane&15
  const int lq   = lane >> 4;          // k-octet = lane>>4  (k = lq*8 + j)

  const v4f vzero = {0.f, 0.f, 0.f, 0.f};
  v4f acc[4][4];
#pragma unroll
  for (int r = 0; r < 4; ++r)
#pragma unroll
    for (int c = 0; c < 4; ++c)
      acc[r][c] = vzero;

  for (int k0 = 0; k0 < DIM; k0 += 32) {
    if constexpr (PRE) {
      const u16* A = (const u16*)Ap;
      const u16* B = (const u16*)Bp;
#pragma unroll
      for (int i = 0; i < 2; ++i) {
        const int li  = i * 256 + tid;    // lane-linear -> LDS dst is base+lane*16
        const int row = li >> 2;          // 4 lanes per 64B row segment
        const int sg  = li & 3;
        gl_lds16(A + (size_t)(m0 + row) * DIM + k0 + sg * 8, &lsA[row * 32 + sg * 8]);
        gl_lds16(B + (size_t)(n0 + row) * DIM + k0 + sg * 8, &lsB[row * 32 + sg * 8]);
      }
    } else {
      const float* A = (const float*)Ap;
      const float* B = (const float*)Bp;
      const int r0 = tid >> 3;
      const int sg = tid & 7;            // 8 lanes x float4 = 128B row segment
#pragma unroll
      for (int i = 0; i < 4; ++i) {
        const int row = r0 + i * 32;
        float4 fa = *(const float4*)(A + (size_t)(m0 + row) * DIM + k0 + sg * 4);
        float4 fb = *(const float4*)(B + (size_t)(n0 + row) * DIM + k0 + sg * 4);
        uint2 wa = {pack2(fa.x, fa.y), pack2(fa.z, fa.w)};
        uint2 wb = {pack2(fb.x, fb.y), pack2(fb.z, fb.w)};
        *(uint2*)&lsA[row * 32 + sg * 4] = wa;
        *(uint2*)&lsB[row * 32 + sg * 4] = wb;
      }
    }
    __syncthreads();

    v8bf af[4], bfv[4];
#pragma unroll
    for (int r = 0; r < 4; ++r)
      af[r] = *(const v8bf*)&lsA[(wr + r * 16 + lm) * 32 + lq * 8];
#pragma unroll
    for (int c = 0; c < 4; ++c)
      bfv[c] = *(const v8bf*)&lsB[(wc + c * 16 + lm) * 32 + lq * 8];

#pragma unroll
    for (int r = 0; r < 4; ++r)
#pragma unroll
      for (int c = 0; c < 4; ++c)
        acc[r][c] = __builtin_amdgcn_mfma_f32_16x16x32_bf16(af[r], bfv[c], acc[r][c], 0, 0, 0);
    __syncthreads();
  }

  // ||tile||^2 : C/D register layout is irrelevant — every element squared once.
  float s = 0.f;
#pragma unroll
  for (int r = 0; r < 4; ++r)
#pragma unroll
    for (int c = 0; c < 4; ++c)
#pragma unroll
      for (int i = 0; i < 4; ++i)
        s += acc[r][c][i] * acc[r][c][i];

#pragma unroll
  for (int off = 32; off > 0; off >>= 1)
    s += __shfl_down(s, off);
  if (lane == 0) red[wave] = s;
  __syncthreads();
  if (tid == 0)
    atomicAdd(d_acc, red[0] + red[1] + red[2] + red[3]);
}

// f32 -> bf16 conversion pass: 8 elems/thread, 16B stores
__global__ __launch_bounds__(256) void cvt_bf16_kernel(
    const float* __restrict__ x, u32* __restrict__ y, int n8)
{
  int i = blockIdx.x * 256 + threadIdx.x;
  if (i >= n8) return;
  const float4* xp = (const float4*)x + (size_t)i * 2;
  float4 f0 = xp[0];
  float4 f1 = xp[1];
  uint4 v = {pack2(f0.x, f0.y), pack2(f0.z, f0.w),
             pack2(f1.x, f1.y), pack2(f1.z, f1.w)};
  ((uint4*)y)[i] = v;
}

__global__ void finalize_kernel(const float* __restrict__ acc, float* __restrict__ out) {
  // fidelity = ||L T^T||_F^2 / B^2
  float fid = acc[0] * (1.0f / ((float)BATCH * (float)BATCH));
  fid = fminf(fmaxf(fid, 0.0f), 1.0f);
  out[0] = 0.1f * fabsf(fid - 0.95f);
}

extern "C" void kernel_launch(void* const* d_in, const int* in_sizes, int n_in,
                              void* d_out, int out_size, void* d_ws, size_t ws_size,
                              hipStream_t stream) {
  const float* L = (const float*)d_in[0];
  const float* T = (const float*)d_in[1];
  float* out = (float*)d_out;

  const size_t NEL      = (size_t)BATCH * DIM;       // 16,777,216 per tensor
  const size_t BYTES_BF = NEL * sizeof(u16);         // 33,554,432

  if (ws_size >= 2 * BYTES_BF + 256) {
    // Path A: pre-convert to bf16 in ws, then m97-style GEMM w/ global_load_lds
    u16*   Lb  = (u16*)d_ws;
    u16*   Tb  = (u16*)((char*)d_ws + BYTES_BF);
    float* acc = (float*)((char*)d_ws + 2 * BYTES_BF);
    hipMemsetAsync(acc, 0, sizeof(float), stream);
    const int n8     = (int)(NEL / 8);               // 2,097,152
    const int blocks = n8 / 256;                     // 8192
    cvt_bf16_kernel<<<blocks, 256, 0, stream>>>(L, (u32*)Lb, n8);
    cvt_bf16_kernel<<<blocks, 256, 0, stream>>>(T, (u32*)Tb, n8);
    gemm_sq_kernel<true><<<dim3(64, 64), 256, 0, stream>>>(Lb, Tb, acc);
    finalize_kernel<<<1, 1, 0, stream>>>(acc, out);
  } else {
    // Path B: ws-less fallback — convert during LDS staging
    float* acc = (ws_size >= sizeof(float)) ? (float*)d_ws : out;
    hipMemsetAsync(acc, 0, sizeof(float), stream);
    gemm_sq_kernel<false><<<dim3(64, 64), 256, 0, stream>>>(L, T, acc);
    finalize_kernel<<<1, 1, 0, stream>>>(acc, out);
  }
}

// Round 2
// 272.439 us; speedup vs baseline: 1.6899x; 1.6899x over previous
//
#include <hip/hip_runtime.h>
#include <stdint.h>

#define BATCH 8192   // GEMM M and N
#define DIM   2048   // GEMM K

typedef unsigned char  u8;
typedef unsigned int   u32;

using v8i = __attribute__((ext_vector_type(8))) int;
using v4f = __attribute__((ext_vector_type(4))) float;

// async global->LDS, 16B per lane. LDS dest is wave-uniform base + lane*16
// (m104/m108) — our staging index li*16 is lane-contiguous by construction.
__device__ __forceinline__ void gl_lds16(const void* g, void* l) {
  __builtin_amdgcn_global_load_lds(
      (const __attribute__((address_space(1))) u32*)g,
      (__attribute__((address_space(3))) u32*)l, 16, 0, 0);
}

// C = L * T^T (M=N=8192, K=2048) in MX-fp8 (e4m3, unit e8m0 scales), never
// materialized: each block accumulates ||128x128 tile||^2 -> one atomicAdd.
//
// LDS layout: row stride = 128 B = exactly 32 banks, so the 16B k-chunk at
// position p of row r holds GLOBAL chunk p ^ (r&7)  (XOR swizzle). Fragment
// reads then hit every bank exactly twice (2-way = free, m136). The swizzle
// lives in the *global* source address of global_load_lds (per-lane vaddr is
// free; the LDS dest ordering is not).
__global__ __launch_bounds__(256) void gemm_sq_fp8(
    const u8* __restrict__ A, const u8* __restrict__ B,
    float* __restrict__ d_acc)
{
  __shared__ u8 lsA[128 * 128];   // 16 KB: [m][k] fp8, k-chunk-swizzled
  __shared__ u8 lsB[128 * 128];   // 16 KB: [n][k]
  __shared__ float red[4];

  const int tid  = threadIdx.x;
  const int m0   = blockIdx.y * 128;
  const int n0   = blockIdx.x * 128;
  const int wave = tid >> 6;
  const int lane = tid & 63;
  const int wr   = (wave >> 1) * 64;   // wave's 64x64 quadrant of the 128x128 tile
  const int wc   = (wave & 1) * 64;
  const int lm   = lane & 15;          // MFMA 16x16x128: m(or n) = lane&15
  const int lq   = lane >> 4;          // k-block: k = lq*32 + reg*4 + byte

  v4f acc[4][4] = {};                  // 64 VGPRs of accumulator
  const int sc = 0x7F7F7F7F;           // e8m0 = 127 -> scale 1.0 in every byte

  for (int k0 = 0; k0 < DIM; k0 += 128) {
    // Stage A,B tiles: 16 KB each = 4 rounds x 256 threads x 16 B.
#pragma unroll
    for (int i = 0; i < 4; ++i) {
      const int li  = i * 256 + tid;
      const int row = li >> 3;          // 8 chunks of 16B per 128B row
      const int p   = li & 7;           // LDS chunk position (lane-contiguous)
      const int g   = p ^ (row & 7);    // global chunk this position holds
      gl_lds16(A + (size_t)(m0 + row) * DIM + k0 + g * 16, &lsA[row * 128 + p * 16]);
      gl_lds16(B + (size_t)(n0 + row) * DIM + k0 + g * 16, &lsB[row * 128 + p * 16]);
    }
    __syncthreads();

    v8i af[4], bf[4];
#pragma unroll
    for (int r = 0; r < 4; ++r) {
      const int row = wr + r * 16 + lm;
      const int sw  = row & 7;
      int4 lo = *(const int4*)&lsA[row * 128 + ((lq * 2)     ^ sw) * 16];
      int4 hi = *(const int4*)&lsA[row * 128 + ((lq * 2 + 1) ^ sw) * 16];
      af[r] = (v8i){lo.x, lo.y, lo.z, lo.w, hi.x, hi.y, hi.z, hi.w};
    }
#pragma unroll
    for (int c = 0; c < 4; ++c) {
      const int row = wc + c * 16 + lm;
      const int sw  = row & 7;
      int4 lo = *(const int4*)&lsB[row * 128 + ((lq * 2)     ^ sw) * 16];
      int4 hi = *(const int4*)&lsB[row * 128 + ((lq * 2 + 1) ^ sw) * 16];
      bf[c] = (v8i){lo.x, lo.y, lo.z, lo.w, hi.x, hi.y, hi.z, hi.w};
    }

#pragma unroll
    for (int r = 0; r < 4; ++r)
#pragma unroll
      for (int c = 0; c < 4; ++c)
        acc[r][c] = __builtin_amdgcn_mfma_scale_f32_16x16x128_f8f6f4(
            af[r], bf[c], acc[r][c],
            /*cbsz=fp8*/ 0, /*blgp=fp8*/ 0,
            /*opsel_a*/ 0, sc, /*opsel_b*/ 0, sc);
    __syncthreads();
  }

  // ||tile||^2 — C/D register layout irrelevant, every element squared once.
  float s = 0.f;
#pragma unroll
  for (int r = 0; r < 4; ++r)
#pragma unroll
    for (int c = 0; c < 4; ++c)
#pragma unroll
      for (int i = 0; i < 4; ++i)
        s += acc[r][c][i] * acc[r][c][i];

#pragma unroll
  for (int off = 32; off > 0; off >>= 1)
    s += __shfl_down(s, off);
  if (lane == 0) red[wave] = s;
  __syncthreads();
  if (tid == 0)
    atomicAdd(d_acc, red[0] + red[1] + red[2] + red[3]);
}

// Fused f32 -> fp8(e4m3) conversion for both tensors: 16 elems/thread,
// 64B read / 16B write per thread, HW RNE via v_cvt_pk_fp8_f32.
__global__ __launch_bounds__(256) void cvt_fp8_kernel(
    const float* __restrict__ L, const float* __restrict__ T,
    uint4* __restrict__ Lo, uint4* __restrict__ To, int n16)
{
  int i = blockIdx.x * 256 + threadIdx.x;
  const float* src;
  uint4* dst;
  if (i < n16) { src = L; dst = Lo; }
  else         { src = T; dst = To; i -= n16; }
  const float4* xp = (const float4*)src + (size_t)i * 4;
  float4 f0 = xp[0], f1 = xp[1], f2 = xp[2], f3 = xp[3];
  u32 w0 = __builtin_amdgcn_cvt_pk_fp8_f32(f0.x, f0.y, 0, false);
  w0     = __builtin_amdgcn_cvt_pk_fp8_f32(f0.z, f0.w, w0, true);
  u32 w1 = __builtin_amdgcn_cvt_pk_fp8_f32(f1.x, f1.y, 0, false);
  w1     = __builtin_amdgcn_cvt_pk_fp8_f32(f1.z, f1.w, w1, true);
  u32 w2 = __builtin_amdgcn_cvt_pk_fp8_f32(f2.x, f2.y, 0, false);
  w2     = __builtin_amdgcn_cvt_pk_fp8_f32(f2.z, f2.w, w2, true);
  u32 w3 = __builtin_amdgcn_cvt_pk_fp8_f32(f3.x, f3.y, 0, false);
  w3     = __builtin_amdgcn_cvt_pk_fp8_f32(f3.z, f3.w, w3, true);
  dst[i] = (uint4){w0, w1, w2, w3};
}

__global__ void finalize_kernel(const float* __restrict__ acc, float* __restrict__ out) {
  // fidelity = ||L T^T||_F^2 / B^2
  float fid = acc[0] * (1.0f / ((float)BATCH * (float)BATCH));
  fid = fminf(fmaxf(fid, 0.0f), 1.0f);
  out[0] = 0.1f * fabsf(fid - 0.95f);
}

extern "C" void kernel_launch(void* const* d_in, const int* in_sizes, int n_in,
                              void* d_out, int out_size, void* d_ws, size_t ws_size,
                              hipStream_t stream) {
  const float* L = (const float*)d_in[0];
  const float* T = (const float*)d_in[1];
  float* out = (float*)d_out;

  const size_t NEL      = (size_t)BATCH * DIM;   // 16,777,216 per tensor
  const size_t BYTES_F8 = NEL;                   // 16 MB per tensor as fp8

  // Round 1 confirmed ws_size >= 64 MB + 256, so this always holds.
  u8*    Lb  = (u8*)d_ws;
  u8*    Tb  = (u8*)d_ws + BYTES_F8;
  float* acc = (float*)((char*)d_ws + 2 * BYTES_F8);

  hipMemsetAsync(acc, 0, sizeof(float), stream);
  const int n16    = (int)(NEL / 16);            // 1,048,576 per tensor
  const int blocks = 2 * n16 / 256;              // 8192 (both tensors, one launch)
  cvt_fp8_kernel<<<blocks, 256, 0, stream>>>(L, T, (uint4*)Lb, (uint4*)Tb, n16);
  gemm_sq_fp8<<<dim3(64, 64), 256, 0, stream>>>(Lb, Tb, acc);
  finalize_kernel<<<1, 1, 0, stream>>>(acc, out);
}

// Round 4
// 234.866 us; speedup vs baseline: 1.9603x; 1.1600x over previous
//
#include <hip/hip_runtime.h>
#include <stdint.h>

#define BATCH 8192   // Gram K dimension
#define DIM   2048   // Gram M and N

typedef unsigned char  u8;
typedef unsigned int   u32;

using v8i  = __attribute__((ext_vector_type(8)))  int;
using v16f = __attribute__((ext_vector_type(16))) float;

// async global->LDS, 16B per lane; dest must be wave-uniform base + lane*16.
__device__ __forceinline__ void gl_lds16(const void* g, void* l) {
  __builtin_amdgcn_global_load_lds(
      (const __attribute__((address_space(1))) u32*)g,
      (__attribute__((address_space(3))) u32*)l, 16, 0, 0);
}

// ---------------------------------------------------------------------------
// Kernel 1: fused transpose + f32->fp8(e4m3). src [8192 b][2048 d] f32 ->
// dst [2048 d][8192 b] fp8. Block tile 64d x 256b. Round-3 bug fixed:
// j in [0,4), brow = j*64 + g*4 (each thread 4 float4 reads, rows covered
// exactly once, no OOB). 4x4 micro-transpose -> word LDS writes, column
// XOR-swizzle (s&12) -> phase A exactly 2-way (free); phase B uint4 reads.
// ---------------------------------------------------------------------------
__global__ __launch_bounds__(256) void tcvt_kernel(
    const float* __restrict__ L, const float* __restrict__ T,
    u8* __restrict__ X, u8* __restrict__ Y)
{
  __shared__ u32 ls[64 * 68];   // [d][68 words]

  const int tid = threadIdx.x;
  int id = blockIdx.x;
  const float* src;
  u8* dst;
  if (id < 1024) { src = L; dst = X; }
  else           { src = T; dst = Y; id -= 1024; }
  const int d0 = (id & 31) * 64;    // 32 d-tiles
  const int b0 = (id >> 5) * 256;   // 32 b-tiles

  const int s  = tid & 15;          // d-slot (d = 4s..4s+3)
  const int g  = tid >> 4;          // b row-group
  const int sw = s & 12;
#pragma unroll
  for (int j = 0; j < 4; ++j) {
    const int brow = j * 64 + g * 4;           // 0..252, each group of 4 once
    float4 f[4];
#pragma unroll
    for (int r = 0; r < 4; ++r)
      f[r] = *(const float4*)(src + (size_t)(b0 + brow + r) * DIM + d0 + s * 4);
    const int w = (j * 16 + g) ^ sw;           // physical word column, 0..63
#pragma unroll
    for (int i = 0; i < 4; ++i) {
      const float* f0 = (const float*)&f[0];
      const float* f1 = (const float*)&f[1];
      const float* f2 = (const float*)&f[2];
      const float* f3 = (const float*)&f[3];
      u32 wv = __builtin_amdgcn_cvt_pk_fp8_f32(f0[i], f1[i], 0, false);
      wv     = __builtin_amdgcn_cvt_pk_fp8_f32(f2[i], f3[i], wv, true);
      ls[(s * 4 + i) * 68 + w] = wv;
    }
  }
  __syncthreads();

  const int d   = tid >> 2;         // output row within tile
  const int g4  = tid & 3;
  const int sw2 = (d >> 2) & 12;
#pragma unroll
  for (int j2 = 0; j2 < 4; ++j2) {
    uint4 v = *(const uint4*)&ls[d * 68 + j2 * 16 + ((g4 * 4) ^ sw2)];
    *(uint4*)(dst + (size_t)(d0 + d) * BATCH + b0 + j2 * 64 + g4 * 16) = v;
  }
}

// ---------------------------------------------------------------------------
// Kernel 2: Gram tile, MATERIALIZED (full K per block -> no cross-term bug).
// Grid 512 = 2 grams x 256 tiles (2 blocks/CU). Each block: 128x128 tile of
// G = M M^T (M = X or Y, [2048][8192] fp8), K=8192, BK=128, wave = 64x64
// quadrant = 2x2 x 2 k-steps of mfma_scale_f32_32x32x64_f8f6f4. Tile stored
// in per-lane-slot order (layout-agnostic; both grams identical permutation).
// LDS: row stride 128B, 16B chunk at pos p of row r holds global chunk
// p ^ (r&7) (round-2's proven swizzle).
// ---------------------------------------------------------------------------
__global__ __launch_bounds__(256, 2) void gram_f8(
    const u8* __restrict__ X, const u8* __restrict__ Y,
    float* __restrict__ Gx, float* __restrict__ Gy)
{
  __shared__ u8 lsI[128 * 128];   // 16 KB
  __shared__ u8 lsJ[128 * 128];   // 16 KB

  const int tid = threadIdx.x;
  const int bid = blockIdx.x;
  const int t   = bid & 255;
  const u8*  src = (bid < 256) ? X : Y;
  float*     dst = (bid < 256) ? Gx : Gy;
  const int i0  = (t >> 4) * 128;
  const int j0  = (t & 15) * 128;

  const int wave = tid >> 6;
  const int lane = tid & 63;
  const int wr = (wave >> 1) * 64;   // quadrant rows (i)
  const int wc = (wave & 1) * 64;    // quadrant cols (j)
  const int lr = lane & 31;          // operand row within 32
  const int kh = lane >> 5;          // k-half selector

  // Staging offsets: 16KB/tile = 4 rounds x 256 lanes x 16B.
  u32 sdst[4], soi[4], soj[4];
#pragma unroll
  for (int rr = 0; rr < 4; ++rr) {
    const int li  = rr * 256 + tid;
    const int row = li >> 3;          // 8 chunks of 16B per 128B row
    const int p   = li & 7;
    const int gc  = p ^ (row & 7);
    sdst[rr] = (u32)(row * 128 + p * 16);
    soi[rr]  = (u32)(i0 + row) * BATCH + gc * 16;
    soj[rr]  = (u32)(j0 + row) * BATCH + gc * 16;
  }

  // Fragment LDS byte addresses (constant per lane): [half][kstep][chunk].
  u32 fa[2][2][2], fb[2][2][2];
#pragma unroll
  for (int h = 0; h < 2; ++h) {
    const int ra = wr + h * 32 + lr;
    const int rb = wc + h * 32 + lr;
#pragma unroll
    for (int ks = 0; ks < 2; ++ks)
#pragma unroll
      for (int c = 0; c < 2; ++c) {
        const int lc = ks * 4 + kh * 2 + c;   // logical 16B chunk, 0..7
        fa[h][ks][c] = (u32)(ra * 128 + (lc ^ (ra & 7)) * 16);
        fb[h][ks][c] = (u32)(rb * 128 + (lc ^ (rb & 7)) * 16);
      }
  }

  v16f acc[2][2] = {};
  const int sc = 0x7F7F7F7F;          // e8m0 = 127 -> scale 1.0

  for (int k0 = 0; k0 < BATCH; k0 += 128) {
#pragma unroll
    for (int rr = 0; rr < 4; ++rr) {
      gl_lds16(src + soi[rr] + k0, lsI + sdst[rr]);
      gl_lds16(src + soj[rr] + k0, lsJ + sdst[rr]);
    }
    __syncthreads();

    v8i a[2][2], b[2][2];
#pragma unroll
    for (int h = 0; h < 2; ++h)
#pragma unroll
      for (int ks = 0; ks < 2; ++ks) {
        int4 lo, hi;
        lo = *(const int4*)&lsI[fa[h][ks][0]];
        hi = *(const int4*)&lsI[fa[h][ks][1]];
        a[h][ks] = (v8i){lo.x, lo.y, lo.z, lo.w, hi.x, hi.y, hi.z, hi.w};
        lo = *(const int4*)&lsJ[fb[h][ks][0]];
        hi = *(const int4*)&lsJ[fb[h][ks][1]];
        b[h][ks] = (v8i){lo.x, lo.y, lo.z, lo.w, hi.x, hi.y, hi.z, hi.w};
      }

#pragma unroll
    for (int ks = 0; ks < 2; ++ks)
#pragma unroll
      for (int h = 0; h < 2; ++h)
#pragma unroll
        for (int hc = 0; hc < 2; ++hc)
          acc[h][hc] = __builtin_amdgcn_mfma_scale_f32_32x32x64_f8f6f4(
              a[h][ks], b[hc][ks], acc[h][hc], 0, 0, 0, sc, 0, sc);
    __syncthreads();
  }

  // Store tile in lane-slot order (both grams identical -> dot is invariant).
  float4* o = (float4*)(dst + (size_t)t * 16384);
#pragma unroll
  for (int h = 0; h < 2; ++h)
#pragma unroll
    for (int hc = 0; hc < 2; ++hc)
#pragma unroll
      for (int r4 = 0; r4 < 4; ++r4) {
        float4 v = {acc[h][hc][r4 * 4 + 0], acc[h][hc][r4 * 4 + 1],
                    acc[h][hc][r4 * 4 + 2], acc[h][hc][r4 * 4 + 3]};
        o[((h * 2 + hc) * 4 + r4) * 256 + tid] = v;
      }
}

// ---------------------------------------------------------------------------
// Kernel 3: elementwise dot of the two materialized Grams -> scalar.
// ---------------------------------------------------------------------------
__global__ __launch_bounds__(256) void dot_kernel(
    const float4* __restrict__ Gx, const float4* __restrict__ Gy,
    float* __restrict__ d_acc)
{
  __shared__ float red[4];
  const int tid  = threadIdx.x;
  const int lane = tid & 63;
  const int i0   = blockIdx.x * 256 + tid;
  float s = 0.0f;
#pragma unroll
  for (int j = 0; j < 4; ++j) {          // 1024 blocks x 256 x 4 = 2048^2/4
    float4 a = Gx[i0 + j * 262144];
    float4 b = Gy[i0 + j * 262144];
    s += a.x * b.x + a.y * b.y + a.z * b.z + a.w * b.w;
  }
#pragma unroll
  for (int off = 32; off > 0; off >>= 1)
    s += __shfl_down(s, off);
  if (lane == 0) red[tid >> 6] = s;
  __syncthreads();
  if (tid == 0)
    atomicAdd(d_acc, red[0] + red[1] + red[2] + red[3]);
}

__global__ void finalize_kernel(const float* __restrict__ acc, float* __restrict__ out) {
  float fid = acc[0] * (1.0f / ((float)BATCH * (float)BATCH));
  fid = fminf(fmaxf(fid, 0.0f), 1.0f);
  out[0] = 0.1f * fabsf(fid - 0.95f);
}

extern "C" void kernel_launch(void* const* d_in, const int* in_sizes, int n_in,
                              void* d_out, int out_size, void* d_ws, size_t ws_size,
                              hipStream_t stream) {
  const float* L = (const float*)d_in[0];
  const float* T = (const float*)d_in[1];
  float* out = (float*)d_out;

  const size_t NEL  = (size_t)BATCH * DIM;       // 16,777,216
  const size_t GEL  = (size_t)DIM * DIM;         // 4,194,304 floats per Gram
  // ws layout: X,Y fp8 (33.5 MB) + Gx,Gy f32 (33.5 MB) + acc = 67,108,868 B.
  // Round 1's Path-A condition proved ws_size >= 67,109,120.
  u8*    X   = (u8*)d_ws;
  u8*    Y   = (u8*)d_ws + NEL;
  float* Gx  = (float*)((char*)d_ws + 2 * NEL);
  float* Gy  = Gx + GEL;
  float* acc = Gy + GEL;

  hipMemsetAsync(acc, 0, sizeof(float), stream);
  tcvt_kernel<<<2048, 256, 0, stream>>>(L, T, X, Y);
  gram_f8<<<512, 256, 0, stream>>>(X, Y, Gx, Gy);
  dot_kernel<<<1024, 256, 0, stream>>>((const float4*)Gx, (const float4*)Gy, acc);
  finalize_kernel<<<1, 1, 0, stream>>>(acc, out);
}